// Round 1
// baseline (397.725 us; speedup 1.0000x reference)
//
#include <hip/hip_runtime.h>
#include <math.h>

#define NH   16
#define HD   64
#define SEQ  2048
#define BAT  2
#define EMB  1024
#define MTOT (BAT*SEQ)   // 4096

typedef __attribute__((ext_vector_type(8))) short bf16x8;
typedef __attribute__((ext_vector_type(4))) float f32x4;

__device__ inline short f2bf(float f) {
    union { float f; unsigned u; } x; x.f = f;
    unsigned r = (x.u + 0x7FFF + ((x.u >> 16) & 1)) >> 16;
    return (short)r;
}

// ---------------------------------------------------------------------------
// Projection GEMM: out[b,h,s,d] (bf16) = rownorm?( X[b,s,:] @ W[e,:] ) * scale
// X: [MTOT, EMB] f32 row-major; W: [EMB, EMB] f32 row-major (torch Linear W)
// Tile: 64 (rows) x 64 (cols = one head), K-step 32, 4 waves (one 16-row
// strip each, 4 n-tiles of 16).
// ---------------------------------------------------------------------------
__global__ __launch_bounds__(256) void proj_kernel(
    const float* __restrict__ X, const float* __restrict__ W,
    short* __restrict__ out, const float* __restrict__ scale_ptr, int do_norm)
{
    __shared__ short As[64][40];   // +8 pad: frag reads stay 16B aligned, banks spread
    __shared__ short Bs[64][40];

    const int m0 = blockIdx.x * 64;
    const int n0 = blockIdx.y * 64;
    const int t = threadIdx.x;
    const int wave = t >> 6, lane = t & 63;
    const int quad = lane >> 4, l16 = lane & 15;

    f32x4 acc[4] = {};

    const int lr = t >> 3;          // 0..31
    const int lc = (t & 7) * 4;     // 0,4,..,28

    for (int k0 = 0; k0 < EMB; k0 += 32) {
#pragma unroll
        for (int p = 0; p < 2; ++p) {
            const int r = lr + p * 32;
            float4 av = *(const float4*)&X[(size_t)(m0 + r) * EMB + k0 + lc];
            As[r][lc + 0] = f2bf(av.x); As[r][lc + 1] = f2bf(av.y);
            As[r][lc + 2] = f2bf(av.z); As[r][lc + 3] = f2bf(av.w);
            float4 bv = *(const float4*)&W[(size_t)(n0 + r) * EMB + k0 + lc];
            Bs[r][lc + 0] = f2bf(bv.x); Bs[r][lc + 1] = f2bf(bv.y);
            Bs[r][lc + 2] = f2bf(bv.z); Bs[r][lc + 3] = f2bf(bv.w);
        }
        __syncthreads();
        bf16x8 a = *(const bf16x8*)&As[wave * 16 + l16][quad * 8];
#pragma unroll
        for (int nt = 0; nt < 4; ++nt) {
            bf16x8 b = *(const bf16x8*)&Bs[nt * 16 + l16][quad * 8];
            acc[nt] = __builtin_amdgcn_mfma_f32_16x16x32_bf16(a, b, acc[nt], 0, 0, 0);
        }
        __syncthreads();
    }

    // Epilogue: optional per-(token,head) L2 norm over the 64 cols of this tile.
    const float scale = scale_ptr ? *scale_ptr : 1.0f;
    float inv[4];
#pragma unroll
    for (int reg = 0; reg < 4; ++reg) {
        if (do_norm) {
            float ss = 0.f;
#pragma unroll
            for (int nt = 0; nt < 4; ++nt) { float v = acc[nt][reg]; ss += v * v; }
            ss += __shfl_xor(ss, 1, 16);
            ss += __shfl_xor(ss, 2, 16);
            ss += __shfl_xor(ss, 4, 16);
            ss += __shfl_xor(ss, 8, 16);
            inv[reg] = scale / fmaxf(sqrtf(ss), 1e-12f);
        } else {
            inv[reg] = scale;
        }
    }
    const int h = n0 >> 6;
#pragma unroll
    for (int nt = 0; nt < 4; ++nt) {
#pragma unroll
        for (int reg = 0; reg < 4; ++reg) {
            const int mg = m0 + wave * 16 + quad * 4 + reg;
            const int b = mg >> 11, s = mg & (SEQ - 1);
            const int d = nt * 16 + l16;
            out[(((size_t)(b * NH + h) * SEQ + s) * HD) + d] = f2bf(acc[nt][reg] * inv[reg]);
        }
    }
}

// ---------------------------------------------------------------------------
// Attention: per (q-tile of 64 rows, bh). Streaming softmax WITHOUT max
// tracking (scores bounded to [-8,8] since |q_hat . k_hat| <= 1, g=8).
// O accum + l accum; final O/l.  q already has g folded in.
// ---------------------------------------------------------------------------
__global__ __launch_bounds__(256) void attn_kernel(
    const short* __restrict__ qw, const short* __restrict__ kw,
    const short* __restrict__ vw, float* __restrict__ out)
{
    __shared__ short Qs[64][72];
    __shared__ short Ks[64][72];
    __shared__ short VT[64][72];   // transposed: VT[d][key]
    __shared__ short Ps[64][72];

    const int qt = blockIdx.x;        // 0..31
    const int bh = blockIdx.y;        // 0..31
    const int b = bh >> 4, h = bh & (NH - 1);
    const size_t base = (size_t)bh * SEQ * HD;

    const int t = threadIdx.x;
    const int wave = t >> 6, lane = t & 63;
    const int quad = lane >> 4, l16 = lane & 15;

    const int lr = t >> 3;          // 0..31
    const int lc = (t & 7) * 8;     // 0,8,..,56

    // Load Q tile (rows qt*64..+63), 8 bf16 (16B) per thread per pass.
#pragma unroll
    for (int p = 0; p < 2; ++p) {
        *(int4*)&Qs[lr + p * 32][lc] =
            *(const int4*)&qw[base + (size_t)(qt * 64 + lr + p * 32) * HD + lc];
    }

    f32x4 o_acc[4] = {};
    float l_run[4] = {0.f, 0.f, 0.f, 0.f};

    __syncthreads();

    for (int kt = 0; kt < SEQ / 64; ++kt) {
        // Stage K tile straight, V tile transposed.
#pragma unroll
        for (int p = 0; p < 2; ++p) {
            const int r = lr + p * 32;
            *(int4*)&Ks[r][lc] =
                *(const int4*)&kw[base + (size_t)(kt * 64 + r) * HD + lc];
            union { int4 v; short s[8]; } tmp;
            tmp.v = *(const int4*)&vw[base + (size_t)(kt * 64 + r) * HD + lc];
#pragma unroll
            for (int j = 0; j < 8; ++j) VT[lc + j][r] = tmp.s[j];
        }
        __syncthreads();

        // S = Q K^T  (64x64, K-dim = HD = 2 MFMA k-steps)
        f32x4 s_acc[4] = {};
#pragma unroll
        for (int ks = 0; ks < 2; ++ks) {
            bf16x8 a = *(const bf16x8*)&Qs[wave * 16 + l16][ks * 32 + quad * 8];
#pragma unroll
            for (int nt = 0; nt < 4; ++nt) {
                bf16x8 bf = *(const bf16x8*)&Ks[nt * 16 + l16][ks * 32 + quad * 8];
                s_acc[nt] = __builtin_amdgcn_mfma_f32_16x16x32_bf16(a, bf, s_acc[nt], 0, 0, 0);
            }
        }

        // p = exp(s) (no max shift; s <= 8 so p <= 2981), accumulate row sums.
#pragma unroll
        for (int reg = 0; reg < 4; ++reg) {
            float rs = 0.f;
#pragma unroll
            for (int nt = 0; nt < 4; ++nt) {
                float p = expf(s_acc[nt][reg]);
                s_acc[nt][reg] = p;
                rs += p;
            }
            rs += __shfl_xor(rs, 1, 16);
            rs += __shfl_xor(rs, 2, 16);
            rs += __shfl_xor(rs, 4, 16);
            rs += __shfl_xor(rs, 8, 16);
            l_run[reg] += rs;
        }

        // P -> LDS in A-operand-friendly row-major layout.
#pragma unroll
        for (int nt = 0; nt < 4; ++nt)
#pragma unroll
            for (int reg = 0; reg < 4; ++reg)
                Ps[wave * 16 + quad * 4 + reg][nt * 16 + l16] = f2bf(s_acc[nt][reg]);
        __syncthreads();

        // O += P V   (A = P rows [q][key], B = VT rows [d][key])
#pragma unroll
        for (int ks = 0; ks < 2; ++ks) {
            bf16x8 a = *(const bf16x8*)&Ps[wave * 16 + l16][ks * 32 + quad * 8];
#pragma unroll
            for (int nt = 0; nt < 4; ++nt) {
                bf16x8 bf = *(const bf16x8*)&VT[nt * 16 + l16][ks * 32 + quad * 8];
                o_acc[nt] = __builtin_amdgcn_mfma_f32_16x16x32_bf16(a, bf, o_acc[nt], 0, 0, 0);
            }
        }
        __syncthreads();   // protect Ks/VT/Ps before next iteration's staging
    }

    // Epilogue: O / l -> out[b, s, h*64 + d]  (f32)
#pragma unroll
    for (int nt = 0; nt < 4; ++nt) {
#pragma unroll
        for (int reg = 0; reg < 4; ++reg) {
            const int srow = qt * 64 + wave * 16 + quad * 4 + reg;
            const int d = nt * 16 + l16;
            out[((size_t)(b * SEQ + srow) * EMB) + h * HD + d] =
                o_acc[nt][reg] / l_run[reg];
        }
    }
}

extern "C" void kernel_launch(void* const* d_in, const int* in_sizes, int n_in,
                              void* d_out, int out_size, void* d_ws, size_t ws_size,
                              hipStream_t stream) {
    (void)in_sizes; (void)n_in; (void)out_size; (void)ws_size;
    const float* x  = (const float*)d_in[0];
    const float* Wq = (const float*)d_in[1];
    const float* Wk = (const float*)d_in[2];
    const float* Wv = (const float*)d_in[3];
    const float* g  = (const float*)d_in[4];
    float* out = (float*)d_out;

    const size_t per = (size_t)BAT * NH * SEQ * HD;   // 4.19M elems
    short* qws = (short*)d_ws;
    short* kws = qws + per;
    short* vws = kws + per;

    dim3 pg(MTOT / 64, EMB / 64);
    proj_kernel<<<pg, 256, 0, stream>>>(x, Wq, qws, g, 1);        // q: norm + g
    proj_kernel<<<pg, 256, 0, stream>>>(x, Wk, kws, nullptr, 1);  // k: norm
    proj_kernel<<<pg, 256, 0, stream>>>(x, Wv, vws, nullptr, 0);  // v: plain

    dim3 ag(SEQ / 64, BAT * NH);
    attn_kernel<<<ag, 256, 0, stream>>>(qws, kws, vws, out);
}

// Round 2
// 362.254 us; speedup vs baseline: 1.0979x; 1.0979x over previous
//
#include <hip/hip_runtime.h>
#include <math.h>

#define NH 16
#define HD 64
#define SEQ 2048
#define BAT 2
#define EMB 1024
#define MTOT (BAT*SEQ)   // 4096
#define NTOT (3*EMB)     // 3072

typedef __attribute__((ext_vector_type(8))) short bf16x8;
typedef __attribute__((ext_vector_type(4))) float f32x4;

__device__ inline short f2bf(float f) {
    union { float f; unsigned u; } x; x.f = f;
    unsigned r = (x.u + 0x7FFF + ((x.u >> 16) & 1)) >> 16;
    return (short)r;
}

// ---------------------------------------------------------------------------
// Prep: f32 -> bf16 for X (4M) and Wq|Wk|Wv (3M) into xb / wb.
// ---------------------------------------------------------------------------
__global__ __launch_bounds__(256) void prep_kernel(
    const float* __restrict__ x, const float* __restrict__ wq,
    const float* __restrict__ wk, const float* __restrict__ wv,
    short* __restrict__ xb, short* __restrict__ wb)
{
    const size_t NX = (size_t)MTOT * EMB;   // 4M floats
    const size_t NW = (size_t)EMB * EMB;    // 1M floats
    const size_t i4 = ((size_t)blockIdx.x * 256 + threadIdx.x) * 4;
    float4 v; short* dst;
    if (i4 < NX) { v = *(const float4*)(x + i4); dst = xb + i4; }
    else {
        size_t j = i4 - NX;
        const float* s = (j < NW) ? wq : (j < 2 * NW) ? wk : wv;
        v = *(const float4*)(s + (j & (NW - 1)));
        dst = wb + j;
    }
    short4 o; o.x = f2bf(v.x); o.y = f2bf(v.y); o.z = f2bf(v.z); o.w = f2bf(v.w);
    *(short4*)dst = o;
}

// ---------------------------------------------------------------------------
// Fused QKV GEMM: C[4096][3072] = X @ [Wq|Wk|Wv]^T, 128x128 tile, BK=32.
// Epilogue: Q -> l2norm * (g*log2e) -> qws[bh][s][d]
//           K -> l2norm           -> kws[bh][s][d]
//           V -> transposed+permuted -> vperm[bh][d][pos(s)]
// pos(s) within 32-block: ((s&12)>>2)*8 + ((s>>4)&1)*4 + (s&3)
// so attn PV B-frags are contiguous b128 in MFMA slot order.
// ---------------------------------------------------------------------------
template<bool CVT>
__global__ __launch_bounds__(256) void qkv_gemm(
    const void* __restrict__ Asrc,
    const void* __restrict__ B0, const void* __restrict__ B1,
    const void* __restrict__ B2,
    short* __restrict__ qws, short* __restrict__ kws, short* __restrict__ vperm,
    const float* __restrict__ gptr)
{
    __shared__ short As[128][40];
    __shared__ short Bs[128][40];
    const int m0 = blockIdx.x * 128, n0 = blockIdx.y * 128;
    const int mat = n0 >> 10;                     // 0=Q,1=K,2=V (uniform)
    const int t = threadIdx.x, wave = t >> 6, lane = t & 63;
    const int quad = lane >> 4, l16 = lane & 15;
    const int wm = (wave & 1) * 64, wn = (wave >> 1) * 64;

    f32x4 acc[4][4] = {};

    const int sr = t >> 1;          // 0..127
    const int sc = (t & 1) * 16;    // 0 | 16

    for (int k0 = 0; k0 < EMB; k0 += 32) {
        if (CVT) {
            const float* xa = (const float*)Asrc;
            const float* wsrc = (mat == 0) ? (const float*)B0
                              : (mat == 1) ? (const float*)B1 : (const float*)B2;
            const int nr = (n0 + sr) & 1023;
            union { int4 v; short s[8]; } pk;
#pragma unroll
            for (int half = 0; half < 2; ++half) {
                float4 a0 = *(const float4*)&xa[(size_t)(m0 + sr) * EMB + k0 + sc + half * 8];
                float4 a1 = *(const float4*)&xa[(size_t)(m0 + sr) * EMB + k0 + sc + half * 8 + 4];
                pk.s[0]=f2bf(a0.x); pk.s[1]=f2bf(a0.y); pk.s[2]=f2bf(a0.z); pk.s[3]=f2bf(a0.w);
                pk.s[4]=f2bf(a1.x); pk.s[5]=f2bf(a1.y); pk.s[6]=f2bf(a1.z); pk.s[7]=f2bf(a1.w);
                *(int4*)&As[sr][sc + half * 8] = pk.v;
                float4 b0 = *(const float4*)&wsrc[(size_t)nr * EMB + k0 + sc + half * 8];
                float4 b1 = *(const float4*)&wsrc[(size_t)nr * EMB + k0 + sc + half * 8 + 4];
                pk.s[0]=f2bf(b0.x); pk.s[1]=f2bf(b0.y); pk.s[2]=f2bf(b0.z); pk.s[3]=f2bf(b0.w);
                pk.s[4]=f2bf(b1.x); pk.s[5]=f2bf(b1.y); pk.s[6]=f2bf(b1.z); pk.s[7]=f2bf(b1.w);
                *(int4*)&Bs[sr][sc + half * 8] = pk.v;
            }
        } else {
            const short* xa = (const short*)Asrc;
            const short* wbp = (const short*)B0;
            *(int4*)&As[sr][sc]     = *(const int4*)&xa[(size_t)(m0 + sr) * EMB + k0 + sc];
            *(int4*)&As[sr][sc + 8] = *(const int4*)&xa[(size_t)(m0 + sr) * EMB + k0 + sc + 8];
            *(int4*)&Bs[sr][sc]     = *(const int4*)&wbp[(size_t)(n0 + sr) * EMB + k0 + sc];
            *(int4*)&Bs[sr][sc + 8] = *(const int4*)&wbp[(size_t)(n0 + sr) * EMB + k0 + sc + 8];
        }
        __syncthreads();
        bf16x8 af[4], bfr[4];
#pragma unroll
        for (int i = 0; i < 4; ++i) af[i]  = *(const bf16x8*)&As[wm + i * 16 + l16][quad * 8];
#pragma unroll
        for (int i = 0; i < 4; ++i) bfr[i] = *(const bf16x8*)&Bs[wn + i * 16 + l16][quad * 8];
#pragma unroll
        for (int mf = 0; mf < 4; ++mf)
#pragma unroll
            for (int nf = 0; nf < 4; ++nf)
                acc[mf][nf] = __builtin_amdgcn_mfma_f32_16x16x32_bf16(af[mf], bfr[nf], acc[mf][nf], 0, 0, 0);
        __syncthreads();
    }

    if (mat < 2) {
        const float scale = (mat == 0) ? gptr[0] * 1.4426950408889634f : 1.0f;
        float inv[4][4];
#pragma unroll
        for (int mf = 0; mf < 4; ++mf)
#pragma unroll
            for (int reg = 0; reg < 4; ++reg) {
                float ss = 0.f;
#pragma unroll
                for (int nf = 0; nf < 4; ++nf) { float v = acc[mf][nf][reg]; ss += v * v; }
                ss += __shfl_xor(ss, 1, 16);
                ss += __shfl_xor(ss, 2, 16);
                ss += __shfl_xor(ss, 4, 16);
                ss += __shfl_xor(ss, 8, 16);
                inv[mf][reg] = scale / fmaxf(sqrtf(ss), 1e-12f);
            }
        short* outp = (mat == 0) ? qws : kws;
#pragma unroll
        for (int mf = 0; mf < 4; ++mf)
#pragma unroll
            for (int nf = 0; nf < 4; ++nf) {
                const int cw = (n0 & 1023) + wn + nf * 16 + l16;
                const int h = cw >> 6, d = cw & 63;
#pragma unroll
                for (int reg = 0; reg < 4; ++reg) {
                    const int s = m0 + wm + mf * 16 + quad * 4 + reg;
                    const int b = s >> 11, sl = s & (SEQ - 1);
                    outp[(((size_t)(b * NH + h) * SEQ + sl) * HD) + d] =
                        f2bf(acc[mf][nf][reg] * inv[mf][reg]);
                }
            }
    } else {
#pragma unroll
        for (int mf = 0; mf < 4; ++mf)
#pragma unroll
            for (int nf = 0; nf < 4; ++nf) {
                const int cw = (n0 & 1023) + wn + nf * 16 + l16;
                const int h = cw >> 6, d = cw & 63;
                const int s = m0 + wm + mf * 16 + quad * 4;   // 4-aligned
                const int b = s >> 11, sl = s & (SEQ - 1);
                const int pos = (sl & ~31) + ((sl & 12) >> 2) * 8 + ((sl >> 4) & 1) * 4;
                short4 o;
                o.x = f2bf(acc[mf][nf][0]); o.y = f2bf(acc[mf][nf][1]);
                o.z = f2bf(acc[mf][nf][2]); o.w = f2bf(acc[mf][nf][3]);
                *(short4*)&vperm[(((size_t)(b * NH + h) * HD + d) * SEQ) + pos] = o;
            }
    }
}

// ---------------------------------------------------------------------------
// Attention: no LDS, no barriers. Computes S^T (A=K, B=Q) so P exits MFMA
// already in A-operand order for PV (custom key<->slot bijection matching
// vperm's layout). Streaming exp2 softmax (scores bounded, g*log2e folded
// into q), divide by l at the end.
// ---------------------------------------------------------------------------
__global__ __launch_bounds__(256) void attn_kernel(
    const short* __restrict__ qws, const short* __restrict__ kws,
    const short* __restrict__ vperm, float* __restrict__ out)
{
    const int qt = blockIdx.x;      // 0..31
    const int bh = blockIdx.y;      // 0..31
    const int b = bh >> 4, h = bh & (NH - 1);
    const int t = threadIdx.x, wave = t >> 6, lane = t & 63;
    const int quad = lane >> 4, l16 = lane & 15;
    const size_t base = (size_t)bh * SEQ * HD;

    // Q fragments (B-operand of S^T), loaded once: q row = qt*64+wave*16+l16
    const short* qp = qws + base + (size_t)(qt * 64 + wave * 16 + l16) * HD + quad * 8;
    const bf16x8 bq0 = *(const bf16x8*)(qp);
    const bf16x8 bq1 = *(const bf16x8*)(qp + 32);

    const short* kp = kws + base + (size_t)l16 * HD + quad * 8;
    const short* vp = vperm + base + (size_t)l16 * SEQ + quad * 8;

    f32x4 o_acc[4] = {};
    float l_run = 0.f;

    for (int kt = 0; kt < SEQ / 64; ++kt) {
        const short* kb = kp + (size_t)kt * 64 * HD;
        f32x4 st[4];
#pragma unroll
        for (int tau = 0; tau < 4; ++tau) {
            bf16x8 a0 = *(const bf16x8*)(kb + (size_t)tau * 16 * HD);
            bf16x8 a1 = *(const bf16x8*)(kb + (size_t)tau * 16 * HD + 32);
            f32x4 z = {};
            z = __builtin_amdgcn_mfma_f32_16x16x32_bf16(a0, bq0, z, 0, 0, 0);
            st[tau] = __builtin_amdgcn_mfma_f32_16x16x32_bf16(a1, bq1, z, 0, 0, 0);
        }
        // exp2 (scores pre-scaled by log2e), row sums, pack P to bf16 frags
        float lp = 0.f;
        bf16x8 pa0, pa1;
#pragma unroll
        for (int tau = 0; tau < 2; ++tau)
#pragma unroll
            for (int r = 0; r < 4; ++r) {
                float p = exp2f(st[tau][r]);
                lp += p;
                pa0[tau * 4 + r] = f2bf(p);
            }
#pragma unroll
        for (int tau = 2; tau < 4; ++tau)
#pragma unroll
            for (int r = 0; r < 4; ++r) {
                float p = exp2f(st[tau][r]);
                lp += p;
                pa1[(tau - 2) * 4 + r] = f2bf(p);
            }
        lp += __shfl_xor(lp, 16);
        lp += __shfl_xor(lp, 32);
        l_run += lp;

        const short* vb = vp + kt * 64;
#pragma unroll
        for (int nt = 0; nt < 4; ++nt) {
            bf16x8 v0 = *(const bf16x8*)(vb + (size_t)nt * 16 * SEQ);
            bf16x8 v1 = *(const bf16x8*)(vb + (size_t)nt * 16 * SEQ + 32);
            o_acc[nt] = __builtin_amdgcn_mfma_f32_16x16x32_bf16(pa0, v0, o_acc[nt], 0, 0, 0);
            o_acc[nt] = __builtin_amdgcn_mfma_f32_16x16x32_bf16(pa1, v1, o_acc[nt], 0, 0, 0);
        }
    }

    // epilogue: O[q][d] layout col=l16=d, row=quad*4+reg=q; l lives at lane q
    float linv[4];
#pragma unroll
    for (int r = 0; r < 4; ++r)
        linv[r] = 1.0f / __shfl(l_run, quad * 4 + r, 64);

    const int srow = qt * 64 + wave * 16 + quad * 4;
    float* op = out + ((size_t)b * SEQ + srow) * EMB + h * HD + l16;
#pragma unroll
    for (int nt = 0; nt < 4; ++nt)
#pragma unroll
        for (int r = 0; r < 4; ++r)
            op[(size_t)r * EMB + nt * 16] = o_acc[nt][r] * linv[r];
}

extern "C" void kernel_launch(void* const* d_in, const int* in_sizes, int n_in,
                              void* d_out, int out_size, void* d_ws, size_t ws_size,
                              hipStream_t stream) {
    (void)in_sizes; (void)n_in; (void)out_size;
    const float* x  = (const float*)d_in[0];
    const float* Wq = (const float*)d_in[1];
    const float* Wk = (const float*)d_in[2];
    const float* Wv = (const float*)d_in[3];
    const float* g  = (const float*)d_in[4];
    float* out = (float*)d_out;

    const size_t per = (size_t)BAT * NH * SEQ * HD;   // 4,194,304 elems
    short* qws   = (short*)d_ws;
    short* kws   = qws + per;
    short* vperm = kws + per;
    short* xb    = vperm + per;                       // 4M elems
    short* wb    = xb + (size_t)MTOT * EMB;           // 3M elems

    const size_t need = (3 * per + (size_t)MTOT * EMB + (size_t)NTOT * EMB) * sizeof(short);
    const bool fits = ws_size >= need;

    if (fits) {
        // 7M floats / 4 per thread / 256 per block = 7168 blocks (exact)
        prep_kernel<<<7168, 256, 0, stream>>>(x, Wq, Wk, Wv, xb, wb);
        qkv_gemm<false><<<dim3(MTOT / 128, NTOT / 128), 256, 0, stream>>>(
            xb, wb, nullptr, nullptr, qws, kws, vperm, g);
    } else {
        qkv_gemm<true><<<dim3(MTOT / 128, NTOT / 128), 256, 0, stream>>>(
            x, Wq, Wk, Wv, qws, kws, vperm, g);
    }
    attn_kernel<<<dim3(SEQ / 64, BAT * NH), 256, 0, stream>>>(qws, kws, vperm, out);
}

// Round 3
// 185.276 us; speedup vs baseline: 2.1467x; 1.9552x over previous
//
#include <hip/hip_runtime.h>
#include <math.h>

#define NH 16
#define HD 64
#define SEQ 2048
#define BAT 2
#define EMB 1024
#define MTOT (BAT*SEQ)   // 4096
#define NTOT (3*EMB)     // 3072

typedef __attribute__((ext_vector_type(8))) short bf16x8;
typedef __attribute__((ext_vector_type(4))) float f32x4;

#define MFMA16(a,b,c) __builtin_amdgcn_mfma_f32_16x16x32_bf16(a,b,c,0,0,0)

__device__ inline short f2bf(float f) {
    union { float f; unsigned u; } x; x.f = f;
    unsigned r = (x.u + 0x7FFF + ((x.u >> 16) & 1)) >> 16;
    return (short)r;
}
// pack two f32 -> bf16x2 (round-half-up; inputs strictly positive, no denorm)
__device__ inline unsigned pack2bf(float a, float b) {
    union { float f; unsigned u; } x, y; x.f = a; y.f = b;
    return ((x.u + 0x8000u) >> 16) | ((y.u + 0x8000u) & 0xffff0000u);
}

typedef const __attribute__((address_space(1))) void* gptr_t;
typedef __attribute__((address_space(3))) void* lptr_t;
// async global->LDS, 16B/lane; LDS dest = wave-uniform base + lane*16
__device__ inline void gload16(const void* g, void* l) {
    __builtin_amdgcn_global_load_lds((gptr_t)(uintptr_t)g, (lptr_t)(uintptr_t)l, 16, 0, 0);
}

// ---------------------------------------------------------------------------
// Prep: f32 -> bf16 for X (4M) and Wq|Wk|Wv (3M) into xb / wb.
// ---------------------------------------------------------------------------
__global__ __launch_bounds__(256) void prep_kernel(
    const float* __restrict__ x, const float* __restrict__ wq,
    const float* __restrict__ wk, const float* __restrict__ wv,
    short* __restrict__ xb, short* __restrict__ wb)
{
    const size_t NX = (size_t)MTOT * EMB;
    const size_t NW = (size_t)EMB * EMB;
    const size_t i4 = ((size_t)blockIdx.x * 256 + threadIdx.x) * 4;
    float4 v; short* dst;
    if (i4 < NX) { v = *(const float4*)(x + i4); dst = xb + i4; }
    else {
        size_t j = i4 - NX;
        const float* s = (j < NW) ? wq : (j < 2 * NW) ? wk : wv;
        v = *(const float4*)(s + (j & (NW - 1)));
        dst = wb + j;
    }
    short4 o; o.x = f2bf(v.x); o.y = f2bf(v.y); o.z = f2bf(v.z); o.w = f2bf(v.w);
    *(short4*)dst = o;
}

// ---------------------------------------------------------------------------
// Shared epilogue: Q/K l2norm -> [bh][s][d]; V -> transposed+permuted
// vperm[bh][d][pos(s)], pos within 32-block = quad(s)*8 + t16(s)*4 + (s&3).
// ---------------------------------------------------------------------------
__device__ inline void qkv_epilogue(
    f32x4 (&acc)[4][4], int m0, int n0, int wm, int wn, int quad, int l16,
    short* __restrict__ qws, short* __restrict__ kws, short* __restrict__ vperm,
    const float* __restrict__ gptr)
{
    const int mat = n0 >> 10;   // 0=Q,1=K,2=V (block-uniform)
    if (mat < 2) {
        const float scale = (mat == 0) ? gptr[0] * 1.4426950408889634f : 1.0f;
        float inv[4][4];
#pragma unroll
        for (int mf = 0; mf < 4; ++mf)
#pragma unroll
            for (int reg = 0; reg < 4; ++reg) {
                float ss = 0.f;
#pragma unroll
                for (int nf = 0; nf < 4; ++nf) { float v = acc[mf][nf][reg]; ss += v * v; }
                ss += __shfl_xor(ss, 1, 16);
                ss += __shfl_xor(ss, 2, 16);
                ss += __shfl_xor(ss, 4, 16);
                ss += __shfl_xor(ss, 8, 16);
                inv[mf][reg] = scale / fmaxf(sqrtf(ss), 1e-12f);
            }
        short* outp = (mat == 0) ? qws : kws;
#pragma unroll
        for (int mf = 0; mf < 4; ++mf)
#pragma unroll
            for (int nf = 0; nf < 4; ++nf) {
                const int cw = (n0 & 1023) + wn + nf * 16 + l16;
                const int h = cw >> 6, d = cw & 63;
#pragma unroll
                for (int reg = 0; reg < 4; ++reg) {
                    const int s = m0 + wm + mf * 16 + quad * 4 + reg;
                    const int b = s >> 11, sl = s & (SEQ - 1);
                    outp[(((size_t)(b * NH + h) * SEQ + sl) * HD) + d] =
                        f2bf(acc[mf][nf][reg] * inv[mf][reg]);
                }
            }
    } else {
#pragma unroll
        for (int mf = 0; mf < 4; ++mf)
#pragma unroll
            for (int nf = 0; nf < 4; ++nf) {
                const int cw = (n0 & 1023) + wn + nf * 16 + l16;
                const int h = cw >> 6, d = cw & 63;
                const int s = m0 + wm + mf * 16 + quad * 4;
                const int b = s >> 11, sl = s & (SEQ - 1);
                const int pos = (sl & ~31) + ((sl & 12) >> 2) * 8 + ((sl >> 4) & 1) * 4;
                short4 o;
                o.x = f2bf(acc[mf][nf][0]); o.y = f2bf(acc[mf][nf][1]);
                o.z = f2bf(acc[mf][nf][2]); o.w = f2bf(acc[mf][nf][3]);
                *(short4*)&vperm[(((size_t)(b * NH + h) * HD + d) * SEQ) + pos] = o;
            }
    }
}

// ---------------------------------------------------------------------------
// Fast fused QKV GEMM (m97 structure): 128x128 tile, BK=64, global_load_lds
// width 16, XOR-swizzled LDS (phys col-group = logical ^ (row&7)).
// ---------------------------------------------------------------------------
__global__ __launch_bounds__(256) void qkv_gemm_fast(
    const short* __restrict__ xb, const short* __restrict__ wb,
    short* __restrict__ qws, short* __restrict__ kws, short* __restrict__ vperm,
    const float* __restrict__ gptr)
{
    __shared__ short As[128 * 64];
    __shared__ short Bs[128 * 64];
    const int m0 = blockIdx.x * 128, n0 = blockIdx.y * 128;
    const int t = threadIdx.x, wave = t >> 6, lane = t & 63;
    const int quad = lane >> 4, l16 = lane & 15;
    const int wm = (wave & 1) * 64, wn = (wave >> 1) * 64;

    // staging decode: instr j covers LDS rows wave*32+j*8 .. +7
    const int srow = wave * 32 + (lane >> 3);           // +j*8 (row&7 invariant)
    const int scol = ((lane & 7) ^ (srow & 7)) * 8;     // swizzled source col
    const short* ga = xb + (size_t)(m0 + srow) * EMB + scol;
    const short* gb = wb + (size_t)(n0 + srow) * EMB + scol;
    short* lA = As + (size_t)wave * 2048;
    short* lB = Bs + (size_t)wave * 2048;

    // frag read bases (row = wm/wn + mf*16 + l16; row&7 == l16&7)
    const short* Aa[2]; const short* Ba[2];
#pragma unroll
    for (int ks = 0; ks < 2; ++ks) {
        const int pc = (ks * 32 + quad * 8) ^ ((l16 & 7) * 8);
        Aa[ks] = As + (wm + l16) * 64 + pc;
        Ba[ks] = Bs + (wn + l16) * 64 + pc;
    }

    f32x4 acc[4][4] = {};

    for (int k0 = 0; k0 < EMB; k0 += 64) {
#pragma unroll
        for (int j = 0; j < 4; ++j) {
            gload16(ga + k0 + (size_t)j * 8 * EMB, lA + j * 512);
            gload16(gb + k0 + (size_t)j * 8 * EMB, lB + j * 512);
        }
        __syncthreads();
#pragma unroll
        for (int ks = 0; ks < 2; ++ks) {
            bf16x8 af[4], bfr[4];
#pragma unroll
            for (int i = 0; i < 4; ++i) af[i]  = *(const bf16x8*)(Aa[ks] + i * 1024);
#pragma unroll
            for (int i = 0; i < 4; ++i) bfr[i] = *(const bf16x8*)(Ba[ks] + i * 1024);
#pragma unroll
            for (int mf = 0; mf < 4; ++mf)
#pragma unroll
                for (int nf = 0; nf < 4; ++nf)
                    acc[mf][nf] = MFMA16(af[mf], bfr[nf], acc[mf][nf]);
        }
        __syncthreads();
    }
    qkv_epilogue(acc, m0, n0, wm, wn, quad, l16, qws, kws, vperm, gptr);
}

// ---------------------------------------------------------------------------
// Fallback fused QKV GEMM with in-kernel f32->bf16 (if ws too small for prep).
// ---------------------------------------------------------------------------
__global__ __launch_bounds__(256) void qkv_gemm_cvt(
    const float* __restrict__ xa, const float* __restrict__ B0,
    const float* __restrict__ B1, const float* __restrict__ B2,
    short* __restrict__ qws, short* __restrict__ kws, short* __restrict__ vperm,
    const float* __restrict__ gptr)
{
    __shared__ short As[128][40];
    __shared__ short Bs[128][40];
    const int m0 = blockIdx.x * 128, n0 = blockIdx.y * 128;
    const int mat = n0 >> 10;
    const int t = threadIdx.x, wave = t >> 6, lane = t & 63;
    const int quad = lane >> 4, l16 = lane & 15;
    const int wm = (wave & 1) * 64, wn = (wave >> 1) * 64;
    f32x4 acc[4][4] = {};
    const int sr = t >> 1, sc = (t & 1) * 16;
    const float* wsrc = (mat == 0) ? B0 : (mat == 1) ? B1 : B2;
    const int nr = (n0 + sr) & 1023;

    for (int k0 = 0; k0 < EMB; k0 += 32) {
        union { int4 v; short s[8]; } pk;
#pragma unroll
        for (int half = 0; half < 2; ++half) {
            float4 a0 = *(const float4*)&xa[(size_t)(m0 + sr) * EMB + k0 + sc + half * 8];
            float4 a1 = *(const float4*)&xa[(size_t)(m0 + sr) * EMB + k0 + sc + half * 8 + 4];
            pk.s[0]=f2bf(a0.x); pk.s[1]=f2bf(a0.y); pk.s[2]=f2bf(a0.z); pk.s[3]=f2bf(a0.w);
            pk.s[4]=f2bf(a1.x); pk.s[5]=f2bf(a1.y); pk.s[6]=f2bf(a1.z); pk.s[7]=f2bf(a1.w);
            *(int4*)&As[sr][sc + half * 8] = pk.v;
            float4 b0 = *(const float4*)&wsrc[(size_t)nr * EMB + k0 + sc + half * 8];
            float4 b1 = *(const float4*)&wsrc[(size_t)nr * EMB + k0 + sc + half * 8 + 4];
            pk.s[0]=f2bf(b0.x); pk.s[1]=f2bf(b0.y); pk.s[2]=f2bf(b0.z); pk.s[3]=f2bf(b0.w);
            pk.s[4]=f2bf(b1.x); pk.s[5]=f2bf(b1.y); pk.s[6]=f2bf(b1.z); pk.s[7]=f2bf(b1.w);
            *(int4*)&Bs[sr][sc + half * 8] = pk.v;
        }
        __syncthreads();
        bf16x8 af[4], bfr[4];
#pragma unroll
        for (int i = 0; i < 4; ++i) af[i]  = *(const bf16x8*)&As[wm + i * 16 + l16][quad * 8];
#pragma unroll
        for (int i = 0; i < 4; ++i) bfr[i] = *(const bf16x8*)&Bs[wn + i * 16 + l16][quad * 8];
#pragma unroll
        for (int mf = 0; mf < 4; ++mf)
#pragma unroll
            for (int nf = 0; nf < 4; ++nf)
                acc[mf][nf] = MFMA16(af[mf], bfr[nf], acc[mf][nf]);
        __syncthreads();
    }
    qkv_epilogue(acc, m0, n0, wm, wn, quad, l16, qws, kws, vperm, gptr);
}

// ---------------------------------------------------------------------------
// Attention: 128-q block (32 q/wave as 2 q-sets), 128-key iters, LDS-staged
// K/V via global_load_lds with XOR swizzle. S^T trick (P exits in A-layout),
// l via ones-MFMA (lands in O's C-layout: no shuffles), exp2 streaming
// softmax (bounded scores), final O/l.
// ---------------------------------------------------------------------------
__global__ __launch_bounds__(256) void attn_kernel(
    const short* __restrict__ qws, const short* __restrict__ kws,
    const short* __restrict__ vperm, float* __restrict__ out)
{
    __shared__ short Kt[128 * 64];   // [key][d], phys col-group ^= key&7
    __shared__ short Vt[64 * 128];   // [d][pos], phys col-group ^= d&15
    const int qt = blockIdx.x;       // 0..15
    const int bh = blockIdx.y;       // 0..31
    const int b = bh >> 4, h = bh & (NH - 1);
    const size_t base = (size_t)bh * SEQ * HD;
    const int t = threadIdx.x, wave = t >> 6, lane = t & 63;
    const int quad = lane >> 4, l16 = lane & 15;

    // Q B-frags, loaded once (scattered; amortized over whole kernel)
    bf16x8 bq[2][2];
    {
        const short* qp = qws + base + (size_t)(qt * 128 + wave * 32 + l16) * HD + quad * 8;
        bq[0][0] = *(const bf16x8*)(qp);
        bq[0][1] = *(const bf16x8*)(qp + 32);
        bq[1][0] = *(const bf16x8*)(qp + 16 * HD);
        bq[1][1] = *(const bf16x8*)(qp + 16 * HD + 32);
    }
    bf16x8 ones;
#pragma unroll
    for (int i = 0; i < 8; ++i) ones[i] = (short)0x3F80;

    // K staging decode: instr j covers LDS rows wave*32+j*8..+7
    const int krow = wave * 32 + (lane >> 3);
    const int kcol = ((lane & 7) ^ (krow & 7)) * 8;
    short* lK = Kt + (size_t)wave * 2048;
    short* lV = Vt + (size_t)wave * 2048;

    // frag read bases
    const short* Ka[2]; const short* Va[4];
#pragma unroll
    for (int ks = 0; ks < 2; ++ks)
        Ka[ks] = Kt + l16 * 64 + ((ks * 32 + quad * 8) ^ ((l16 & 7) * 8));
#pragma unroll
    for (int g = 0; g < 4; ++g)
        Va[g] = Vt + l16 * 128 + (((g * 4 + quad) ^ l16) * 8);

    f32x4 o_acc[2][4] = {};
    f32x4 l_acc[2] = {};

    for (int kt = 0; kt < SEQ / 128; ++kt) {
        const short* kg = kws + base + (size_t)(kt * 128 + krow) * HD + kcol;
#pragma unroll
        for (int j = 0; j < 4; ++j)
            gload16(kg + (size_t)j * 8 * HD, lK + j * 512);
#pragma unroll
        for (int j = 0; j < 4; ++j) {
            const int d = wave * 16 + j * 4 + (lane >> 4);
            const int lg = (lane & 15) ^ (d & 15);
            gload16(vperm + base + (size_t)d * SEQ + kt * 128 + lg * 8, lV + j * 512);
        }
        __syncthreads();

#pragma unroll
        for (int g = 0; g < 4; ++g) {
            // S^T for the two 16-key tiles of this 32-key group
            f32x4 st[2][2];
#pragma unroll
            for (int p = 0; p < 2; ++p) {
                const int tau = 2 * g + p;
                bf16x8 a0 = *(const bf16x8*)(Ka[0] + tau * 1024);
                bf16x8 a1 = *(const bf16x8*)(Ka[1] + tau * 1024);
#pragma unroll
                for (int qs = 0; qs < 2; ++qs) {
                    f32x4 z = {};
                    z = MFMA16(a0, bq[qs][0], z);
                    st[p][qs] = MFMA16(a1, bq[qs][1], z);
                }
            }
            // V frags for this group (shared by both q-sets)
            bf16x8 vf[4];
#pragma unroll
            for (int nt = 0; nt < 4; ++nt)
                vf[nt] = *(const bf16x8*)(Va[g] + nt * 2048);
            // exp2 + pack -> P A-frags; l and O via MFMA
#pragma unroll
            for (int qs = 0; qs < 2; ++qs) {
                bf16x8 pa;
                unsigned* pu = (unsigned*)&pa;
                pu[0] = pack2bf(exp2f(st[0][qs][0]), exp2f(st[0][qs][1]));
                pu[1] = pack2bf(exp2f(st[0][qs][2]), exp2f(st[0][qs][3]));
                pu[2] = pack2bf(exp2f(st[1][qs][0]), exp2f(st[1][qs][1]));
                pu[3] = pack2bf(exp2f(st[1][qs][2]), exp2f(st[1][qs][3]));
                l_acc[qs] = MFMA16(pa, ones, l_acc[qs]);
#pragma unroll
                for (int nt = 0; nt < 4; ++nt)
                    o_acc[qs][nt] = MFMA16(pa, vf[nt], o_acc[qs][nt]);
            }
        }
        __syncthreads();
    }

    // epilogue: O and l share layout (q = quad*4+reg, col = l16)
    float linv[2][4];
#pragma unroll
    for (int qs = 0; qs < 2; ++qs)
#pragma unroll
        for (int r = 0; r < 4; ++r)
            linv[qs][r] = 1.0f / l_acc[qs][r];

    float* ob = out + ((size_t)b * SEQ + qt * 128 + wave * 32 + quad * 4) * EMB + h * HD + l16;
#pragma unroll
    for (int qs = 0; qs < 2; ++qs)
#pragma unroll
        for (int nt = 0; nt < 4; ++nt)
#pragma unroll
            for (int r = 0; r < 4; ++r)
                ob[(size_t)(qs * 16 + r) * EMB + nt * 16] = o_acc[qs][nt][r] * linv[qs][r];
}

extern "C" void kernel_launch(void* const* d_in, const int* in_sizes, int n_in,
                              void* d_out, int out_size, void* d_ws, size_t ws_size,
                              hipStream_t stream) {
    (void)in_sizes; (void)n_in; (void)out_size;
    const float* x  = (const float*)d_in[0];
    const float* Wq = (const float*)d_in[1];
    const float* Wk = (const float*)d_in[2];
    const float* Wv = (const float*)d_in[3];
    const float* g  = (const float*)d_in[4];
    float* out = (float*)d_out;

    const size_t per = (size_t)BAT * NH * SEQ * HD;   // 4,194,304 elems
    short* qws   = (short*)d_ws;
    short* kws   = qws + per;
    short* vperm = kws + per;
    short* xb    = vperm + per;
    short* wb    = xb + (size_t)MTOT * EMB;

    const size_t need = (3 * per + (size_t)MTOT * EMB + (size_t)NTOT * EMB) * sizeof(short);

    if (ws_size >= need) {
        prep_kernel<<<7168, 256, 0, stream>>>(x, Wq, Wk, Wv, xb, wb);
        qkv_gemm_fast<<<dim3(MTOT / 128, NTOT / 128), 256, 0, stream>>>(
            xb, wb, qws, kws, vperm, g);
    } else {
        qkv_gemm_cvt<<<dim3(MTOT / 128, NTOT / 128), 256, 0, stream>>>(
            x, Wq, Wk, Wv, qws, kws, vperm, g);
    }
    attn_kernel<<<dim3(SEQ / 128, BAT * NH), 256, 0, stream>>>(qws, kws, vperm, out);
}

// Round 4
// 163.508 us; speedup vs baseline: 2.4325x; 1.1331x over previous
//
#include <hip/hip_runtime.h>
#include <math.h>

#define NH 16
#define HD 64
#define SEQ 2048
#define BAT 2
#define EMB 1024
#define MTOT (BAT*SEQ)   // 4096
#define NTOT (3*EMB)     // 3072

typedef __attribute__((ext_vector_type(8))) short bf16x8;
typedef __attribute__((ext_vector_type(4))) float f32x4;

#define MFMA16(a,b,c) __builtin_amdgcn_mfma_f32_16x16x32_bf16(a,b,c,0,0,0)

__device__ inline short f2bf(float f) {
    union { float f; unsigned u; } x; x.f = f;
    unsigned r = (x.u + 0x7FFF + ((x.u >> 16) & 1)) >> 16;
    return (short)r;
}

// raw v_exp_f32 (inputs bounded to [-12,12]: no range/denorm handling needed)
__device__ inline float fast_exp2(float x) {
#if __has_builtin(__builtin_amdgcn_exp2f)
    return __builtin_amdgcn_exp2f(x);
#else
    float r; asm("v_exp_f32 %0, %1" : "=v"(r) : "v"(x)); return r;
#endif
}

// pack two rounded bf16 into one dword: 2x v_add + 1x v_perm
__device__ inline unsigned pack2bf(float a, float b) {
    union { float f; unsigned u; } x, y; x.f = a; y.f = b;
    return __builtin_amdgcn_perm(y.u + 0x8000u, x.u + 0x8000u, 0x07060302u);
}

typedef const __attribute__((address_space(1))) void* gp_t;
typedef __attribute__((address_space(3))) void* lp_t;
// async global->LDS, 16B/lane; LDS dest = wave-uniform base + lane*16
__device__ inline void gload16(const void* g, void* l) {
    __builtin_amdgcn_global_load_lds((gp_t)(uintptr_t)g, (lp_t)(uintptr_t)l, 16, 0, 0);
}

// ---------------------------------------------------------------------------
// Prep: f32 -> bf16 for X (4M) and Wq|Wk|Wv (3M) into scratch carved из d_out.
// ---------------------------------------------------------------------------
__global__ __launch_bounds__(256) void prep_kernel(
    const float* __restrict__ x, const float* __restrict__ wq,
    const float* __restrict__ wk, const float* __restrict__ wv,
    short* __restrict__ xb, short* __restrict__ wb)
{
    const size_t NX = (size_t)MTOT * EMB;
    const size_t NW = (size_t)EMB * EMB;
    const size_t i4 = ((size_t)blockIdx.x * 256 + threadIdx.x) * 4;
    float4 v; short* dst;
    if (i4 < NX) { v = *(const float4*)(x + i4); dst = xb + i4; }
    else {
        size_t j = i4 - NX;
        const float* s = (j < NW) ? wq : (j < 2 * NW) ? wk : wv;
        v = *(const float4*)(s + (j & (NW - 1)));
        dst = wb + j;
    }
    short4 o; o.x = f2bf(v.x); o.y = f2bf(v.y); o.z = f2bf(v.z); o.w = f2bf(v.w);
    *(short4*)dst = o;
}

// ---------------------------------------------------------------------------
// Fused QKV GEMM (m97 structure): 128x128 tile, BK=64, global_load_lds w=16,
// XOR-swizzled LDS. Epilogue: Q l2norm*(g*log2e), K l2norm -> [bh][s][d];
// V transposed+permuted -> vperm[bh][d][pos(s)].
// ---------------------------------------------------------------------------
__global__ __launch_bounds__(256) void qkv_gemm_fast(
    const short* __restrict__ xb, const short* __restrict__ wb,
    short* __restrict__ qws, short* __restrict__ kws, short* __restrict__ vperm,
    const float* __restrict__ gptr)
{
    __shared__ short As[128 * 64];
    __shared__ short Bs[128 * 64];
    const int m0 = blockIdx.x * 128, n0 = blockIdx.y * 128;
    const int t = threadIdx.x, wave = t >> 6, lane = t & 63;
    const int quad = lane >> 4, l16 = lane & 15;
    const int wm = (wave & 1) * 64, wn = (wave >> 1) * 64;

    // staging decode: instr j covers LDS rows wave*32+j*8 .. +7
    const int srow = wave * 32 + (lane >> 3);
    const int scol = ((lane & 7) ^ (srow & 7)) * 8;
    const short* ga = xb + (size_t)(m0 + srow) * EMB + scol;
    const short* gb = wb + (size_t)(n0 + srow) * EMB + scol;
    short* lA = As + (size_t)wave * 2048;
    short* lB = Bs + (size_t)wave * 2048;

    const short* Aa[2]; const short* Ba[2];
#pragma unroll
    for (int ks = 0; ks < 2; ++ks) {
        const int pc = (ks * 32 + quad * 8) ^ ((l16 & 7) * 8);
        Aa[ks] = As + (wm + l16) * 64 + pc;
        Ba[ks] = Bs + (wn + l16) * 64 + pc;
    }

    f32x4 acc[4][4] = {};

    for (int k0 = 0; k0 < EMB; k0 += 64) {
#pragma unroll
        for (int j = 0; j < 4; ++j) {
            gload16(ga + k0 + (size_t)j * 8 * EMB, lA + j * 512);
            gload16(gb + k0 + (size_t)j * 8 * EMB, lB + j * 512);
        }
        __syncthreads();
#pragma unroll
        for (int ks = 0; ks < 2; ++ks) {
            bf16x8 af[4], bfr[4];
#pragma unroll
            for (int i = 0; i < 4; ++i) af[i]  = *(const bf16x8*)(Aa[ks] + i * 1024);
#pragma unroll
            for (int i = 0; i < 4; ++i) bfr[i] = *(const bf16x8*)(Ba[ks] + i * 1024);
#pragma unroll
            for (int mf = 0; mf < 4; ++mf)
#pragma unroll
                for (int nf = 0; nf < 4; ++nf)
                    acc[mf][nf] = MFMA16(af[mf], bfr[nf], acc[mf][nf]);
        }
        __syncthreads();
    }

    // ---- epilogue ----
    const int mat = n0 >> 10;   // 0=Q,1=K,2=V (block-uniform)
    if (mat < 2) {
        const float scale = (mat == 0) ? gptr[0] * 1.4426950408889634f : 1.0f;
        float inv[4][4];
#pragma unroll
        for (int mf = 0; mf < 4; ++mf)
#pragma unroll
            for (int reg = 0; reg < 4; ++reg) {
                float ss = 0.f;
#pragma unroll
                for (int nf = 0; nf < 4; ++nf) { float v = acc[mf][nf][reg]; ss += v * v; }
                ss += __shfl_xor(ss, 1, 16);
                ss += __shfl_xor(ss, 2, 16);
                ss += __shfl_xor(ss, 4, 16);
                ss += __shfl_xor(ss, 8, 16);
                inv[mf][reg] = scale / fmaxf(sqrtf(ss), 1e-12f);
            }
        short* outp = (mat == 0) ? qws : kws;
#pragma unroll
        for (int mf = 0; mf < 4; ++mf)
#pragma unroll
            for (int nf = 0; nf < 4; ++nf) {
                const int cw = (n0 & 1023) + wn + nf * 16 + l16;
                const int h = cw >> 6, d = cw & 63;
#pragma unroll
                for (int reg = 0; reg < 4; ++reg) {
                    const int s = m0 + wm + mf * 16 + quad * 4 + reg;
                    const int b = s >> 11, sl = s & (SEQ - 1);
                    outp[(((size_t)(b * NH + h) * SEQ + sl) * HD) + d] =
                        f2bf(acc[mf][nf][reg] * inv[mf][reg]);
                }
            }
    } else {
#pragma unroll
        for (int mf = 0; mf < 4; ++mf)
#pragma unroll
            for (int nf = 0; nf < 4; ++nf) {
                const int cw = (n0 & 1023) + wn + nf * 16 + l16;
                const int h = cw >> 6, d = cw & 63;
                const int s = m0 + wm + mf * 16 + quad * 4;
                const int b = s >> 11, sl = s & (SEQ - 1);
                const int pos = (sl & ~31) + ((sl & 12) >> 2) * 8 + ((sl >> 4) & 1) * 4;
                short4 o;
                o.x = f2bf(acc[mf][nf][0]); o.y = f2bf(acc[mf][nf][1]);
                o.z = f2bf(acc[mf][nf][2]); o.w = f2bf(acc[mf][nf][3]);
                *(short4*)&vperm[(((size_t)(b * NH + h) * HD + d) * SEQ) + pos] = o;
            }
    }
}

// ---------------------------------------------------------------------------
// Attention: 128-q block (2 q-sets/wave), 128-key iters, double-buffered
// K/V LDS via global_load_lds (XOR swizzle). S^T trick (P exits in A-layout),
// l via ones-MFMA, raw v_exp_f32 softmax (bounded scores), final O/l.
// Grid: 1-D 512, bh = id&31 -> all q-tiles of a bh co-located per XCD.
// ---------------------------------------------------------------------------
__global__ __launch_bounds__(256) void attn_kernel(
    const short* __restrict__ qws, const short* __restrict__ kws,
    const short* __restrict__ vperm, float* __restrict__ out)
{
    __shared__ short Kt[2][128 * 64];   // [key][d], phys col-group ^= key&7
    __shared__ short Vt[2][64 * 128];   // [d][pos], phys col-group ^= d&15
    const int id = blockIdx.x;
    const int bh = id & 31, qt = id >> 5;
    const int b = bh >> 4, h = bh & (NH - 1);
    const size_t base = (size_t)bh * SEQ * HD;
    const int t = threadIdx.x, wave = t >> 6, lane = t & 63;
    const int quad = lane >> 4, l16 = lane & 15;

    // Q B-frags, loaded once
    bf16x8 bq[2][2];
    {
        const short* qp = qws + base + (size_t)(qt * 128 + wave * 32 + l16) * HD + quad * 8;
        bq[0][0] = *(const bf16x8*)(qp);
        bq[0][1] = *(const bf16x8*)(qp + 32);
        bq[1][0] = *(const bf16x8*)(qp + 16 * HD);
        bq[1][1] = *(const bf16x8*)(qp + 16 * HD + 32);
    }
    bf16x8 ones;
#pragma unroll
    for (int i = 0; i < 8; ++i) ones[i] = (short)0x3F80;

    // staging decode
    const int krow = wave * 32 + (lane >> 3);
    const int kcol = ((lane & 7) ^ (krow & 7)) * 8;
    const int vd = wave * 16 + (lane >> 4);          // +j*4
    const int vg = (lane & 15);

    // frag read offsets (buffer-relative)
    int pcK[2], pcV[4];
#pragma unroll
    for (int ks = 0; ks < 2; ++ks)
        pcK[ks] = l16 * 64 + ((ks * 32 + quad * 8) ^ ((l16 & 7) * 8));
#pragma unroll
    for (int g = 0; g < 4; ++g)
        pcV[g] = l16 * 128 + (((g * 4 + quad) ^ l16) * 8);

    f32x4 o_acc[2][4] = {};
    f32x4 l_acc[2] = {};

    // stage tile kt into buffer p
    auto stage = [&](int kt, int p) {
        const short* kg = kws + base + (size_t)(kt * 128 + krow) * HD + kcol;
        short* lK = &Kt[p][0] + (size_t)wave * 2048;
        short* lV = &Vt[p][0] + (size_t)wave * 2048;
#pragma unroll
        for (int j = 0; j < 4; ++j)
            gload16(kg + (size_t)j * 8 * HD, lK + j * 512);
#pragma unroll
        for (int j = 0; j < 4; ++j) {
            const int d = vd + j * 4;
            const int lg = vg ^ (d & 15);
            gload16(vperm + base + (size_t)d * SEQ + kt * 128 + lg * 8, lV + j * 512);
        }
    };

    stage(0, 0);
    __syncthreads();   // tile 0 resident

    for (int kt = 0; kt < SEQ / 128; ++kt) {
        const int p = kt & 1;
        if (kt + 1 < SEQ / 128) stage(kt + 1, p ^ 1);   // prefetch overlaps compute
        const short* Kp = &Kt[p][0];
        const short* Vp = &Vt[p][0];

#pragma unroll
        for (int g = 0; g < 4; ++g) {
            f32x4 st[2][2];
#pragma unroll
            for (int pp = 0; pp < 2; ++pp) {
                const int tau = 2 * g + pp;
                bf16x8 a0 = *(const bf16x8*)(Kp + pcK[0] + tau * 1024);
                bf16x8 a1 = *(const bf16x8*)(Kp + pcK[1] + tau * 1024);
#pragma unroll
                for (int qs = 0; qs < 2; ++qs) {
                    f32x4 z = {};
                    z = MFMA16(a0, bq[qs][0], z);
                    st[pp][qs] = MFMA16(a1, bq[qs][1], z);
                }
            }
            bf16x8 vf[4];
#pragma unroll
            for (int nt = 0; nt < 4; ++nt)
                vf[nt] = *(const bf16x8*)(Vp + pcV[g] + nt * 2048);
#pragma unroll
            for (int qs = 0; qs < 2; ++qs) {
                bf16x8 pa;
                unsigned* pu = (unsigned*)&pa;
                pu[0] = pack2bf(fast_exp2(st[0][qs][0]), fast_exp2(st[0][qs][1]));
                pu[1] = pack2bf(fast_exp2(st[0][qs][2]), fast_exp2(st[0][qs][3]));
                pu[2] = pack2bf(fast_exp2(st[1][qs][0]), fast_exp2(st[1][qs][1]));
                pu[3] = pack2bf(fast_exp2(st[1][qs][2]), fast_exp2(st[1][qs][3]));
                l_acc[qs] = MFMA16(pa, ones, l_acc[qs]);
#pragma unroll
                for (int nt = 0; nt < 4; ++nt)
                    o_acc[qs][nt] = MFMA16(pa, vf[nt], o_acc[qs][nt]);
            }
        }
        __syncthreads();   // drains prefetch (after compute) + guards reuse of p
    }

    float linv[2][4];
#pragma unroll
    for (int qs = 0; qs < 2; ++qs)
#pragma unroll
        for (int r = 0; r < 4; ++r)
            linv[qs][r] = 1.0f / l_acc[qs][r];

    float* ob = out + ((size_t)b * SEQ + qt * 128 + wave * 32 + quad * 4) * EMB + h * HD + l16;
#pragma unroll
    for (int qs = 0; qs < 2; ++qs)
#pragma unroll
        for (int nt = 0; nt < 4; ++nt)
#pragma unroll
            for (int r = 0; r < 4; ++r)
                ob[(size_t)(qs * 16 + r) * EMB + nt * 16] = o_acc[qs][nt][r] * linv[qs][r];
}

extern "C" void kernel_launch(void* const* d_in, const int* in_sizes, int n_in,
                              void* d_out, int out_size, void* d_ws, size_t ws_size,
                              hipStream_t stream) {
    (void)in_sizes; (void)n_in; (void)out_size; (void)ws_size;
    const float* x  = (const float*)d_in[0];
    const float* Wq = (const float*)d_in[1];
    const float* Wk = (const float*)d_in[2];
    const float* Wv = (const float*)d_in[3];
    const float* g  = (const float*)d_in[4];
    float* out = (float*)d_out;

    const size_t per = (size_t)BAT * NH * SEQ * HD;   // 4,194,304 elems
    short* qws   = (short*)d_ws;
    short* kws   = qws + per;
    short* vperm = kws + per;                          // ws: 25.2 MB total

    // bf16 staging lives in d_out (16.8 MB; attn fully overwrites it last)
    short* xb = (short*)out;                           // 4M shorts
    short* wb = xb + (size_t)MTOT * EMB;               // 3M shorts (7M <= 8.38M cap)

    prep_kernel<<<7168, 256, 0, stream>>>(x, Wq, Wk, Wv, xb, wb);
    qkv_gemm_fast<<<dim3(MTOT / 128, NTOT / 128), 256, 0, stream>>>(
        xb, wb, qws, kws, vperm, g);
    attn_kernel<<<(SEQ / 128) * BAT * NH, 256, 0, stream>>>(qws, kws, vperm, out);
}